// Round 9
// baseline (427.667 us; speedup 1.0000x reference)
//
#include <hip/hip_runtime.h>
#include <hip/hip_bf16.h>

typedef short short8 __attribute__((ext_vector_type(8)));   // 8 bf16 = 4 VGPRs
typedef float f32x4 __attribute__((ext_vector_type(4)));
typedef unsigned short u16;

__device__ __forceinline__ unsigned short f2bf(float f) {
  unsigned int u = __float_as_uint(f);
  u += 0x7fffu + ((u >> 16) & 1u);    // round-to-nearest-even
  return (unsigned short)(u >> 16);
}

// async 16B global->LDS (dest = wave-uniform base + lane*16)
__device__ __forceinline__ void glds16(const void* g, void* l) {
  __builtin_amdgcn_global_load_lds(
      (const __attribute__((address_space(1))) unsigned int*)g,
      (__attribute__((address_space(3))) unsigned int*)l, 16, 0, 0);
}

// Full drain (vmcnt=0, expcnt=0, lgkmcnt=0) BEFORE s_barrier (r8-proven
// fence for glds16 staging).
__device__ __forceinline__ void drain_then_sync() {
  __builtin_amdgcn_s_waitcnt(0);
  __syncthreads();
}

// Device-scope grid barrier over N blocks. Monotonic counter (zeroed by a
// memset node each launch): release-add, acquire-spin. Cross-XCD visibility
// per G16: __threadfence() (device scope) on both sides. Stale counter from
// a partial rocprof replay makes the spin fall through instantly (>=N) --
// the failure mode is a fast pass-through, never a hang. Spin bail-out cap
// bounds worst-case pathology to ~0.1s instead of a dead container.
__device__ __forceinline__ void gridbar(unsigned* c, unsigned n) {
  __syncthreads();                         // all my waves' phase work issued
  if (threadIdx.x == 0) {
    __threadfence();                       // release: my block's writes visible
    __hip_atomic_fetch_add(c, 1u, __ATOMIC_RELEASE, __HIP_MEMORY_SCOPE_AGENT);
    unsigned spins = 0;
    while (__hip_atomic_load(c, __ATOMIC_ACQUIRE, __HIP_MEMORY_SCOPE_AGENT) < n) {
      __builtin_amdgcn_s_sleep(2);
      if (++spins > 2000000u) break;       // bail-out; normal wait ~1k spins
    }
  }
  __syncthreads();                         // broadcast barrier completion
  __threadfence();                         // acquire: invalidate stale caches
}

// ---- ONE persistent kernel: prep -> gridbar -> gemm -> gridbar -> attn ----
// R9 rationale: kernel-work budget (attn 50.3 measured; gemm 8.3us MFMA floor
// -> ~25 at 35% util; prep ~11 BW-bound) sums to ~88us, but dur_us is
// 147-152 across ALL rounds, with the non-attn residue pinned at ~95us
// regardless of structure. The ~50us gap is inter-dispatch overhead in the
// timed region -- removable only by fusion. 512 blocks x 512 thr = exactly
// 2 blocks/CU (48KB LDS, launch_bounds(512,4) caps VGPR<=128), so all blocks
// are co-resident by capacity and the software barrier cannot starve.
__global__ __launch_bounds__(512, 4) void fused_all(
    const float4* __restrict__ q, const float4* __restrict__ m,
    const float4* __restrict__ wq, const float4* __restrict__ wk,
    u16* __restrict__ qb, u16* __restrict__ mb_,
    u16* __restrict__ wqb, u16* __restrict__ wkb,
    u16* __restrict__ Qp, u16* __restrict__ Kp,
    float* __restrict__ out, unsigned* __restrict__ bars) {
  __shared__ u16 smem[24576];   // 48KB: gemm 3-buf ring; attn reuses 16KB
  const int bid = blockIdx.x;
  const int t = threadIdx.x;
  const int lane = t & 63, wave = t >> 6;     // 8 waves
  const int l15 = lane & 15, quad = lane >> 4;

  // ================= phase 1: prep (grid-stride, 2637824 16B items) ========
  {
    const float c = 0.18033688011112042f;  // 1/(8*ln2)
    for (int i = bid * 512 + t; i < 2637824; i += 262144) {
      if (i < 1048576) {
        float4 v = q[i];
        ushort4 o; o.x = f2bf(v.x); o.y = f2bf(v.y); o.z = f2bf(v.z); o.w = f2bf(v.w);
        ((ushort4*)qb)[i] = o;
      } else if (i < 2097152) {
        float4 v = m[i - 1048576];
        ushort4 o; o.x = f2bf(v.x); o.y = f2bf(v.y); o.z = f2bf(v.z); o.w = f2bf(v.w);
        ((ushort4*)mb_)[i - 1048576] = o;
      } else if (i < 2359296) {
        float4 v = wq[i - 2097152];
        ushort4 o; o.x = f2bf(v.x * c); o.y = f2bf(v.y * c);
        o.z = f2bf(v.z * c); o.w = f2bf(v.w * c);
        ((ushort4*)wqb)[i - 2097152] = o;
      } else if (i < 2621440) {
        float4 v = wk[i - 2359296];
        ushort4 o; o.x = f2bf(v.x); o.y = f2bf(v.y); o.z = f2bf(v.z); o.w = f2bf(v.w);
        ((ushort4*)wkb)[i - 2359296] = o;
      } else {
        ((float4*)out)[i - 2621440] = (float4){0.f, 0.f, 0.f, 0.f};
      }
    }
  }
  gridbar(bars + 0, 512);

  // ================= phase 2: gemm (R8-proven 3-buf ring, verbatim) ========
  {
    u16* const As0 = smem;             // 3 x 4096 u16
    u16* const Bs0 = smem + 12288;     // 3 x 4096 u16
    const int x = bid & 63, y = bid >> 6;     // old (blockIdx.x, blockIdx.y)
    const int zz = x & 1;
    const u16* A = zz ? mb_ : qb;
    const u16* B = zz ? wkb : wqb;
    u16* C = zz ? Kp : Qp;
    const int mb = (x >> 1) * 128;
    const int nb = y * 128;
    const int wm = (wave & 1) * 64;
    const int wn = (wave >> 1) * 32;

    const int srow = lane >> 2;                                  // 0..15
    const int sq = (lane & 3) ^ (srow & 3) ^ ((srow >> 2) & 3);  // inverse swz
    const size_t arow = (size_t)(mb + wave * 16 + srow) * 1024 + sq * 8;
    const size_t brow = (size_t)(nb + wave * 16 + srow) * 1024 + sq * 8;
    const int ldst = wave * 512 + lane * 8;

    const int sw2 = (l15 & 3) ^ ((l15 >> 2) & 3);
    const int rcol = (quad ^ sw2) * 8;

    f32x4 acc[4][2];
#pragma unroll
    for (int i = 0; i < 4; i++)
#pragma unroll
      for (int j = 0; j < 2; j++) acc[i][j] = (f32x4){0.f, 0.f, 0.f, 0.f};

    glds16(A + arow, &As0[ldst]);
    glds16(B + brow, &Bs0[ldst]);
    glds16(A + arow + 32, &As0[4096 + ldst]);
    glds16(B + brow + 32, &Bs0[4096 + ldst]);

#pragma unroll
    for (int it = 0; it < 32; ++it) {
      if (it != 31) asm volatile("s_waitcnt vmcnt(2)" ::: "memory");
      else          asm volatile("s_waitcnt vmcnt(0)" ::: "memory");
      __builtin_amdgcn_s_barrier();
      __builtin_amdgcn_sched_barrier(0);
      if (it <= 29) {
        const int bf_ = (it + 2) % 3;
        glds16(A + arow + (size_t)(it + 2) * 32, &As0[bf_ * 4096 + ldst]);
        glds16(B + brow + (size_t)(it + 2) * 32, &Bs0[bf_ * 4096 + ldst]);
      }
      const u16* as = &As0[(it % 3) * 4096];
      const u16* bs = &Bs0[(it % 3) * 4096];
      short8 af[4], bfr[2];
#pragma unroll
      for (int mi = 0; mi < 4; mi++)
        af[mi] = *(const short8*)&as[(wm + mi * 16 + l15) * 32 + rcol];
#pragma unroll
      for (int ni = 0; ni < 2; ni++)
        bfr[ni] = *(const short8*)&bs[(wn + ni * 16 + l15) * 32 + rcol];
#pragma unroll
      for (int mi = 0; mi < 4; mi++)
#pragma unroll
        for (int ni = 0; ni < 2; ni++)
          acc[mi][ni] = __builtin_amdgcn_mfma_f32_16x16x32_bf16(
              af[mi], bfr[ni], acc[mi][ni], 0, 0, 0);
    }

#pragma unroll
    for (int mi = 0; mi < 4; mi++)
#pragma unroll
      for (int r = 0; r < 4; r++) {
        const int row = mb + wm + mi * 16 + quad * 4 + r;
        const size_t base = (size_t)row * 1024 + nb + wn;
#pragma unroll
        for (int ni = 0; ni < 2; ni++)
          C[base + ni * 16 + l15] = f2bf(acc[mi][ni][r]);
      }
  }
  gridbar(bars + 1, 512);

  // ================= phase 3: attn (8 waves: wave = K-chunk; 2 aa/block) ====
  {
    u16* const qs0 = smem;            // 2 x 4096 u16 (16KB) double buffer
    const int b = bid & 7;            // batch b -> XCD b: Kp[b] L2-local
    const int h = (bid >> 3) & 15;
    const int sub = bid >> 7;         // 0..3 -> aa pair
    const int kwave = wave * 64;      // 8 waves cover all 512 K rows

    // K fragments for 4 k-tiles x (d-lo, d-hi), in registers throughout
    short8 klo[4], khi[4];
#pragma unroll
    for (int tt = 0; tt < 4; tt++) {
      const short8* kg = (const short8*)(Kp + (size_t)(b * 512 + kwave + tt * 16 + l15) * 1024
                                         + h * 64 + quad * 8);
      klo[tt] = kg[0];
      khi[tt] = kg[4];
    }

    const int srow = lane >> 3;
    const int scol = ((lane & 7) ^ srow) * 8;
    const int sw = l15 & 7;
    const int colLo = (quad ^ sw) * 8;
    const int colHi = ((4 + quad) ^ sw) * 8;
    const int rrow = l15 * 64;

    for (int a2 = 0; a2 < 2; ++a2) {
      const int aa = sub * 2 + a2;
      const u16* qbase = Qp + (size_t)(aa * 512) * 1024 + h * 64;
      float cs0 = 0.f, cs1 = 0.f, cs2 = 0.f, cs3 = 0.f;

      // stage tile 0: one 8-row group per wave (8 waves x 8 rows = 64)
      glds16(qbase + (size_t)(wave * 8 + srow) * 1024 + scol,
             &qs0[wave * 512 + lane * 8]);

      for (int i = 0; i < 8; i++) {
        drain_then_sync();
        if (i < 7) {
          glds16(qbase + (size_t)((i + 1) * 64 + wave * 8 + srow) * 1024 + scol,
                 &qs0[((i + 1) & 1) * 4096 + wave * 512 + lane * 8]);
        }
        const u16* buf = &qs0[(i & 1) * 4096];
#pragma unroll
        for (int qt = 0; qt < 4; qt++) {
          short8 alo = *(const short8*)&buf[qt * 1024 + rrow + colLo];
          short8 ahi = *(const short8*)&buf[qt * 1024 + rrow + colHi];
          f32x4 ac0 = (f32x4){0.f, 0.f, 0.f, 0.f};
          f32x4 ac1 = ac0, ac2 = ac0, ac3 = ac0;
          ac0 = __builtin_amdgcn_mfma_f32_16x16x32_bf16(alo, klo[0], ac0, 0, 0, 0);
          ac0 = __builtin_amdgcn_mfma_f32_16x16x32_bf16(ahi, khi[0], ac0, 0, 0, 0);
          ac1 = __builtin_amdgcn_mfma_f32_16x16x32_bf16(alo, klo[1], ac1, 0, 0, 0);
          ac1 = __builtin_amdgcn_mfma_f32_16x16x32_bf16(ahi, khi[1], ac1, 0, 0, 0);
          ac2 = __builtin_amdgcn_mfma_f32_16x16x32_bf16(alo, klo[2], ac2, 0, 0, 0);
          ac2 = __builtin_amdgcn_mfma_f32_16x16x32_bf16(ahi, khi[2], ac2, 0, 0, 0);
          ac3 = __builtin_amdgcn_mfma_f32_16x16x32_bf16(alo, klo[3], ac3, 0, 0, 0);
          ac3 = __builtin_amdgcn_mfma_f32_16x16x32_bf16(ahi, khi[3], ac3, 0, 0, 0);
#pragma unroll
          for (int r = 0; r < 4; r++) {
            cs0 += __builtin_amdgcn_exp2f(ac0[r]);
            cs1 += __builtin_amdgcn_exp2f(ac1[r]);
            cs2 += __builtin_amdgcn_exp2f(ac2[r]);
            cs3 += __builtin_amdgcn_exp2f(ac3[r]);
          }
        }
      }
      cs0 += __shfl_xor(cs0, 16); cs0 += __shfl_xor(cs0, 32);
      cs1 += __shfl_xor(cs1, 16); cs1 += __shfl_xor(cs1, 32);
      cs2 += __shfl_xor(cs2, 16); cs2 += __shfl_xor(cs2, 32);
      cs3 += __shfl_xor(cs3, 16); cs3 += __shfl_xor(cs3, 32);
      const float v = quad == 0 ? cs0 : quad == 1 ? cs1 : quad == 2 ? cs2 : cs3;
      atomicAdd(out + (size_t)b * 8192 + h * 512 + kwave + quad * 16 + l15, __logf(v));
      // next aa reuses qs: safe -- at i=7-top barrier all waves finished
      // reading buf0; i=7 reads buf1 only, so the aa+1 prologue write to
      // buf0 cannot race any reader.
    }
  }
}

extern "C" void kernel_launch(void* const* d_in, const int* in_sizes, int n_in,
                              void* d_out, int out_size, void* d_ws, size_t ws_size,
                              hipStream_t stream) {
  const float* query  = (const float*)d_in[0];  // [8,512,1024]
  const float* memory = (const float*)d_in[1];  // [8,512,1024]
  const float* wq     = (const float*)d_in[2];  // [1024,1024]
  const float* wk     = (const float*)d_in[3];  // [1024,1024]
  float* out = (float*)d_out;                   // [8,16,512]

  char* ws = (char*)d_ws;
  const size_t MB = 1024 * 1024;
  u16* qb  = (u16*)(ws);             // 8 MB bf16 query
  u16* mb_ = (u16*)(ws + 8  * MB);   // 8 MB bf16 memory
  u16* wqb = (u16*)(ws + 16 * MB);   // 2 MB bf16 W_Q * c
  u16* wkb = (u16*)(ws + 18 * MB);   // 2 MB bf16 W_K
  u16* Qp  = (u16*)(ws + 20 * MB);   // 8 MB projected Q'
  u16* Kp  = (u16*)(ws + 28 * MB);   // 8 MB projected K
  unsigned* bars = (unsigned*)(ws + 36 * MB);   // 2 grid-barrier counters

  hipMemsetAsync(bars, 0, 16, stream);          // graph-capturable memset node
  fused_all<<<512, 512, 0, stream>>>(
      (const float4*)query, (const float4*)memory,
      (const float4*)wq, (const float4*)wk,
      qb, mb_, wqb, wkb, Qp, Kp, out, bars);
}